// Round 9
// baseline (185.633 us; speedup 1.0000x reference)
//
#include <hip/hip_runtime.h>

#define NPG 64
#define IN 16
#define DM 128
#define NOUT 64
#define EPG 4096
#define BN_EPS 1e-5f

// ---------------------------------------------------------------------------
// Two kernels, ONE boundary, no atomics, no memset:
//  K1 k_front (160 blocks x 512 thr):
//    blocks 0..127  conv per graph -> ppart      (r7-proven path)
//    blocks 128..159 deep-K gemm (32 blocks: 4 gtile x 2 ftile x 4 kslice,
//                    K=1280 each, sub-K split over 4 wave-groups, dbuf)
//                    -> part[4][128][128]  (256 KB total)
//  K2 k_tail (64 blocks x 512 thr): per-block REDUNDANT tail:
//    reduce part+ppart+bm0 -> relu -> BN0 (block-local stats via shfl+LDS)
//    -> M1 -> BN1 -> M2 -> BN2 -> O (2 graphs per block).
//    BN hops are __syncthreads, not grid syncs (r8 lesson: sync COUNT is
//    the only remaining lever; redundant M costs 13.6us < 3 boundaries).
// ---------------------------------------------------------------------------

__global__ __launch_bounds__(512) void k_front(
    const float* __restrict__ x, const float* __restrict__ ew,
    const float* __restrict__ W1, const float* __restrict__ b1,
    const float* __restrict__ W2, const float* __restrict__ b2,
    const float* __restrict__ Wm0,
    float* __restrict__ part, float* __restrict__ ppart)
{
    __shared__ __align__(16) float u[16128];   // 63KB union
    const int bid = blockIdx.x, t = threadIdx.x;

    if (bid < 128) {
        // ---------------- conv path (one block per graph, r7 verbatim) ------
        float* ew_s     = u;             // [i][j] 4096
        float* x_s      = u + 4096;      // x^T [k][i] 1024
        float* W1_s     = u + 5120;      // [k][f] 2048
        float* P_s      = u + 7168;      // [i][f] 8192
        float* b1_s     = u + 15360;     // 128
        float* dinv_s   = u + 15488;     // 64
        float* t_s      = u + 15552;     // 64
        float* zp       = u + 4096;      // overlay: 16*132
        float* z_full   = u + 15616;     // 128
        float* pooled_s = u + 15744;     // 128
        float* pp4      = u + 4096;      // overlay 2: 512
        const int g = bid;
        {
            const float4* ew4 = (const float4*)(ew + g * EPG);
            float4* ews4 = (float4*)ew_s;
            ews4[t]       = ew4[t];
            ews4[t + 512] = ew4[t + 512];
            if (t < 256) {
                const int xi = t & 63, k4 = (t >> 6) * 4;
                float4 xv = *(const float4*)(x + g * NPG * IN + xi * IN + k4);
                x_s[(k4 + 0) * 64 + xi] = xv.x;
                x_s[(k4 + 1) * 64 + xi] = xv.y;
                x_s[(k4 + 2) * 64 + xi] = xv.z;
                x_s[(k4 + 3) * 64 + xi] = xv.w;
            }
            ((float4*)W1_s)[t] = ((const float4*)W1)[t];
            if (t < 128) b1_s[t] = b1[t];
        }
        __syncthreads();

        if (t < NPG) {
            float s = 0.f;
            #pragma unroll 8
            for (int i = 0; i < NPG; i++) s += ew_s[i * NPG + t];
            dinv_s[t] = (s > 0.f) ? rsqrtf(s) : 0.f;
        }
        __syncthreads();

        {   // t_s[i] = dinv_i * (sum_j ew[i,j] dinv_j) / 64
            const int j = t & 63, q = t >> 6;
            const float dj = dinv_s[j];
            for (int i = q * 8; i < q * 8 + 8; i++) {
                float vv = ew_s[i * NPG + j] * dj;
                #pragma unroll
                for (int off = 32; off > 0; off >>= 1) vv += __shfl_down(vv, off, 64);
                if (j == 0) t_s[i] = dinv_s[i] * vv * (1.f / 64.f);
            }
        }

        {   // P' = dinv_i * (x @ W1)
            const int it = t & 15, ft = t >> 4;
            const int i0 = it * 4, f0 = ft * 4;
            float accp[4][4];
            #pragma unroll
            for (int a = 0; a < 4; a++)
                #pragma unroll
                for (int c = 0; c < 4; c++) accp[a][c] = 0.f;
            #pragma unroll
            for (int k = 0; k < IN; k++) {
                const float4 a4 = *(const float4*)(x_s + k * 64 + i0);
                const float4 b4 = *(const float4*)(W1_s + k * DM + f0);
                const float av[4] = {a4.x, a4.y, a4.z, a4.w};
                const float bv[4] = {b4.x, b4.y, b4.z, b4.w};
                #pragma unroll
                for (int a = 0; a < 4; a++)
                    #pragma unroll
                    for (int c = 0; c < 4; c++) accp[a][c] += av[a] * bv[c];
            }
            #pragma unroll
            for (int a = 0; a < 4; a++) {
                const float di = dinv_s[i0 + a];
                *(float4*)(P_s + (i0 + a) * DM + f0) =
                    make_float4(di * accp[a][0], di * accp[a][1],
                                di * accp[a][2], di * accp[a][3]);
            }
        }
        __syncthreads();

        {   // aggregation + z-partials
            const int jt = t & 15, ft = t >> 4;
            const int j0 = jt * 4, f0 = ft * 4;
            float acc[4][4];
            #pragma unroll
            for (int a = 0; a < 4; a++)
                #pragma unroll
                for (int c = 0; c < 4; c++) acc[a][c] = 0.f;
            #pragma unroll 4
            for (int k = 0; k < 64; k++) {
                const float4 a4 = *(const float4*)(ew_s + k * 64 + j0);
                const float4 b4 = *(const float4*)(P_s + k * DM + f0);
                const float av[4] = {a4.x, a4.y, a4.z, a4.w};
                const float bv[4] = {b4.x, b4.y, b4.z, b4.w};
                #pragma unroll
                for (int a = 0; a < 4; a++)
                    #pragma unroll
                    for (int c = 0; c < 4; c++) acc[a][c] += av[a] * bv[c];
            }
            float zpart[4];
            #pragma unroll
            for (int c = 0; c < 4; c++) zpart[c] = 0.f;
            #pragma unroll
            for (int a = 0; a < 4; a++) {
                const float dj = dinv_s[j0 + a], tj = t_s[j0 + a];
                #pragma unroll
                for (int c = 0; c < 4; c++) {
                    float h = fmaxf(dj * acc[a][c] + b1_s[f0 + c], 0.f);
                    zpart[c] += tj * h;
                }
            }
            *(float4*)(zp + jt * 132 + f0) =
                make_float4(zpart[0], zpart[1], zpart[2], zpart[3]);
        }
        __syncthreads();

        if (t < 128) {
            float s = 0.f;
            #pragma unroll
            for (int jt = 0; jt < 16; jt++) s += zp[jt * 132 + t];
            z_full[t] = s;
        }
        __syncthreads();

        {   // pooled = relu(z @ W2 + b2)
            const int c = t & 127, kh = t >> 7;
            float acc = 0.f;
            #pragma unroll 8
            for (int k = kh * 32; k < kh * 32 + 32; k++)
                acc += z_full[k] * W2[k * DM + c];
            pp4[kh * 128 + c] = acc;
        }
        __syncthreads();
        if (t < 128)
            pooled_s[t] = fmaxf(pp4[t] + pp4[128 + t] + pp4[256 + t] + pp4[384 + t]
                                + b2[t], 0.f);
        __syncthreads();

        {   // ppart = pooled @ Wm0[0:128,:]
            const int f = t & 127, kh = t >> 7;
            float acc = 0.f;
            #pragma unroll 8
            for (int k = kh * 32; k < kh * 32 + 32; k++)
                acc += pooled_s[k] * Wm0[k * DM + f];
            pp4[kh * 128 + f] = acc;
        }
        __syncthreads();
        if (t < 128)
            ppart[g * DM + t] = pp4[t] + pp4[128 + t] + pp4[256 + t] + pp4[384 + t];
    } else {
        // -------- deep-K gemm: 32 blocks, tile 32g x 64f, K=1280 --------
        const int c = bid - 128;
        const int gt = c & 3, ftb = (c >> 2) & 1, kc = c >> 3;
        const int gB = gt * 32, fB = ftb * 64, K0 = kc * 1280;
        float* a_s = u;              // 2 x [64k][36] = 4608
        float* b_s = u + 4608;       // 2 x [64k][68] = 8704

        const int kq = t >> 7;       // sub-K wave-group 0..3
        const int id = t & 127;
        const int g0 = (id & 7) * 4;       // 8 x 4 = 32 g
        const int f0 = (id >> 3) * 4;      // 16 x 4 = 64 f
        const int sgg = t & 31;            // A-staging row
        const int skk = (t >> 5) * 4;      // A-staging k base

        float acc[4][4];
        #pragma unroll
        for (int i = 0; i < 4; i++)
            #pragma unroll
            for (int j = 0; j < 4; j++) acc[i][j] = 0.f;

        float4 rA, rB0, rB1;
        auto LOADF = [&](int ci) {
            int K = K0 + ci * 64 + skk;
            const float* src = (K < 1024) ? (x + (size_t)(gB + sgg) * 1024 + K)
                                          : (ew + (size_t)(gB + sgg) * 4096 + (K - 1024));
            rA = *(const float4*)src;
            int kk0 = t >> 4, ff0 = (t & 15) * 4;
            rB0 = *(const float4*)(Wm0 + (size_t)(128 + K0 + ci * 64 + kk0) * 128
                                   + fB + ff0);
            int kk1 = 32 + (t >> 4);
            rB1 = *(const float4*)(Wm0 + (size_t)(128 + K0 + ci * 64 + kk1) * 128
                                   + fB + ff0);
        };
        auto STOREF = [&](int buf) {
            float* ab = a_s + buf * 2304;
            ab[(skk + 0) * 36 + sgg] = fmaxf(rA.x, 0.f);
            ab[(skk + 1) * 36 + sgg] = fmaxf(rA.y, 0.f);
            ab[(skk + 2) * 36 + sgg] = fmaxf(rA.z, 0.f);
            ab[(skk + 3) * 36 + sgg] = fmaxf(rA.w, 0.f);
            float* bb = b_s + buf * 4352;
            int kk0 = t >> 4, ff0 = (t & 15) * 4;
            *(float4*)(bb + kk0 * 68 + ff0) = rB0;
            *(float4*)(bb + (32 + kk0) * 68 + ff0) = rB1;
        };
        auto COMPF = [&](int buf) {
            const float* ab = a_s + buf * 2304;
            const float* bb = b_s + buf * 4352;
            #pragma unroll 4
            for (int k2 = 0; k2 < 16; k2++) {
                const int k = kq * 16 + k2;
                const float4 a = *(const float4*)(ab + k * 36 + g0);
                const float4 b = *(const float4*)(bb + k * 68 + f0);
                const float av[4] = {a.x, a.y, a.z, a.w};
                const float bv[4] = {b.x, b.y, b.z, b.w};
                #pragma unroll
                for (int i = 0; i < 4; i++)
                    #pragma unroll
                    for (int j = 0; j < 4; j++) acc[i][j] += av[i] * bv[j];
            }
        };

        LOADF(0); STOREF(0);
        __syncthreads();
        for (int ci = 0; ci < 20; ci++) {
            if (ci < 19) LOADF(ci + 1);
            COMPF(ci & 1);
            if (ci < 19) STOREF((ci + 1) & 1);
            __syncthreads();
        }
        // sub-K reduce via LDS overlay (a_s/b_s dead)
        float* red = u;                   // 3 * 128 * 16 = 6144
        if (kq > 0) {
            float* r = red + (kq - 1) * 2048 + id * 16;
            #pragma unroll
            for (int i = 0; i < 4; i++)
                #pragma unroll
                for (int j = 0; j < 4; j++) r[i * 4 + j] = acc[i][j];
        }
        __syncthreads();
        if (kq == 0) {
            #pragma unroll
            for (int i = 0; i < 4; i++)
                #pragma unroll
                for (int j = 0; j < 4; j++)
                    acc[i][j] += red[id * 16 + i * 4 + j]
                               + red[2048 + id * 16 + i * 4 + j]
                               + red[4096 + id * 16 + i * 4 + j];
            #pragma unroll
            for (int i = 0; i < 4; i++)
                *(float4*)(part + (size_t)kc * 16384
                           + (size_t)(gB + g0 + i) * 128 + fB + f0) =
                    make_float4(acc[i][0], acc[i][1], acc[i][2], acc[i][3]);
        }
    }
}

// ---------------------------------------------------------------------------
// One redundant MLP layer inside k_tail. ht is [k][g] (transposed activations,
// BN-normalized). Thread tile 4g x 8f (512 thr = 32 gthr x 16 fgrp) keeps the
// inner loop VALU-bound (1 ds_read_b128 per 32 FMA). Stats: shfl over the 32
// gthr lanes (low 5 bits of lane id) -> sp; block-local everything.
// ---------------------------------------------------------------------------
__device__ __forceinline__ void mlayer(
    float* ht, float* sp1, float* sp2, float* scs, float* shs, int t,
    const float* __restrict__ W, const float* __restrict__ bias,
    const float* __restrict__ gbn, const float* __restrict__ bbn)
{
    const int gthr = t & 31, f0 = (t >> 5) * 8;
    const int g0 = gthr * 4;
    float acc[4][8];
    #pragma unroll
    for (int i = 0; i < 4; i++)
        #pragma unroll
        for (int j = 0; j < 8; j++) acc[i][j] = 0.f;
    #pragma unroll 2
    for (int k = 0; k < 128; k++) {
        const float4 a  = *(const float4*)(ht + k * 128 + g0);
        const float4 w0 = *(const float4*)(W + (size_t)k * 128 + f0);
        const float4 w1 = *(const float4*)(W + (size_t)k * 128 + f0 + 4);
        const float av[4] = {a.x, a.y, a.z, a.w};
        const float wv[8] = {w0.x, w0.y, w0.z, w0.w, w1.x, w1.y, w1.z, w1.w};
        #pragma unroll
        for (int i = 0; i < 4; i++)
            #pragma unroll
            for (int j = 0; j < 8; j++) acc[i][j] += av[i] * wv[j];
    }
    const float4 bA = *(const float4*)(bias + f0);
    const float4 bB = *(const float4*)(bias + f0 + 4);
    const float bv[8] = {bA.x, bA.y, bA.z, bA.w, bB.x, bB.y, bB.z, bB.w};
    float v[4][8];
    #pragma unroll
    for (int i = 0; i < 4; i++)
        #pragma unroll
        for (int j = 0; j < 8; j++) v[i][j] = fmaxf(acc[i][j] + bv[j], 0.f);
    // block-local BN stats
    float p1[8], p2[8];
    #pragma unroll
    for (int j = 0; j < 8; j++) {
        p1[j] = v[0][j] + v[1][j] + v[2][j] + v[3][j];
        p2[j] = v[0][j] * v[0][j] + v[1][j] * v[1][j]
              + v[2][j] * v[2][j] + v[3][j] * v[3][j];
    }
    #pragma unroll
    for (int off = 16; off > 0; off >>= 1)
        #pragma unroll
        for (int j = 0; j < 8; j++) {
            p1[j] += __shfl_xor(p1[j], off, 64);
            p2[j] += __shfl_xor(p2[j], off, 64);
        }
    if (gthr == 0)
        #pragma unroll
        for (int j = 0; j < 8; j++) { sp1[f0 + j] = p1[j]; sp2[f0 + j] = p2[j]; }
    __syncthreads();
    if (t < 128) {
        float m = sp1[t] * (1.f / 128.f);
        float var = sp2[t] * (1.f / 128.f) - m * m;
        float s = gbn[t] * rsqrtf(var + BN_EPS);
        scs[t] = s; shs[t] = bbn[t] - m * s;
    }
    __syncthreads();
    // normalized transposed write-back (float4 over g: conflict-free)
    #pragma unroll
    for (int j = 0; j < 8; j++) {
        const float sj = scs[f0 + j], hj = shs[f0 + j];
        *(float4*)(ht + (f0 + j) * 128 + g0) =
            make_float4(v[0][j] * sj + hj, v[1][j] * sj + hj,
                        v[2][j] * sj + hj, v[3][j] * sj + hj);
    }
    __syncthreads();
}

__global__ __launch_bounds__(512) void k_tail(
    const float* __restrict__ part, const float* __restrict__ ppart,
    const float* __restrict__ bm0,
    const float* __restrict__ gbn0, const float* __restrict__ bbn0,
    const float* __restrict__ Wm1, const float* __restrict__ bm1,
    const float* __restrict__ gbn1, const float* __restrict__ bbn1,
    const float* __restrict__ Wm2, const float* __restrict__ bm2,
    const float* __restrict__ gbn2, const float* __restrict__ bbn2,
    const float* __restrict__ Wo, const float* __restrict__ bo,
    float* __restrict__ out)
{
    __shared__ __align__(16) float ht[128 * 128];   // 64KB [k][g]
    __shared__ float sp1[128], sp2[128], scs[128], shs[128];
    const int bid = blockIdx.x, t = threadIdx.x;
    const int gthr = t & 31, f0 = (t >> 5) * 8;
    const int g0 = gthr * 4;

    // ---- phase 0: redundant reduce -> raw v0 tile + BN0 stats ----
    float vr[4][8];
    {
        const float4 bA = *(const float4*)(bm0 + f0);
        const float4 bB = *(const float4*)(bm0 + f0 + 4);
        #pragma unroll
        for (int i = 0; i < 4; i++) {
            const size_t ro = (size_t)(g0 + i) * 128 + f0;
            float4 sA = *(const float4*)(ppart + ro);
            float4 sB = *(const float4*)(ppart + ro + 4);
            sA.x += bA.x; sA.y += bA.y; sA.z += bA.z; sA.w += bA.w;
            sB.x += bB.x; sB.y += bB.y; sB.z += bB.z; sB.w += bB.w;
            #pragma unroll
            for (int kc = 0; kc < 4; kc++) {
                float4 pA = *(const float4*)(part + kc * 16384 + ro);
                float4 pB = *(const float4*)(part + kc * 16384 + ro + 4);
                sA.x += pA.x; sA.y += pA.y; sA.z += pA.z; sA.w += pA.w;
                sB.x += pB.x; sB.y += pB.y; sB.z += pB.z; sB.w += pB.w;
            }
            vr[i][0] = fmaxf(sA.x, 0.f); vr[i][1] = fmaxf(sA.y, 0.f);
            vr[i][2] = fmaxf(sA.z, 0.f); vr[i][3] = fmaxf(sA.w, 0.f);
            vr[i][4] = fmaxf(sB.x, 0.f); vr[i][5] = fmaxf(sB.y, 0.f);
            vr[i][6] = fmaxf(sB.z, 0.f); vr[i][7] = fmaxf(sB.w, 0.f);
        }
    }
    {   // stats0
        float p1[8], p2[8];
        #pragma unroll
        for (int j = 0; j < 8; j++) {
            p1[j] = vr[0][j] + vr[1][j] + vr[2][j] + vr[3][j];
            p2[j] = vr[0][j] * vr[0][j] + vr[1][j] * vr[1][j]
                  + vr[2][j] * vr[2][j] + vr[3][j] * vr[3][j];
        }
        #pragma unroll
        for (int off = 16; off > 0; off >>= 1)
            #pragma unroll
            for (int j = 0; j < 8; j++) {
                p1[j] += __shfl_xor(p1[j], off, 64);
                p2[j] += __shfl_xor(p2[j], off, 64);
            }
        if (gthr == 0)
            #pragma unroll
            for (int j = 0; j < 8; j++) { sp1[f0 + j] = p1[j]; sp2[f0 + j] = p2[j]; }
    }
    // raw transposed write (normalize in place after stats)
    #pragma unroll
    for (int j = 0; j < 8; j++)
        *(float4*)(ht + (f0 + j) * 128 + g0) =
            make_float4(vr[0][j], vr[1][j], vr[2][j], vr[3][j]);
    __syncthreads();
    if (t < 128) {
        float m = sp1[t] * (1.f / 128.f);
        float var = sp2[t] * (1.f / 128.f) - m * m;
        float s = gbn0[t] * rsqrtf(var + BN_EPS);
        scs[t] = s; shs[t] = bbn0[t] - m * s;
    }
    __syncthreads();
    {   // in-place row normalize: thread (k = t>>2, seg = (t&3)*32)
        const int k = t >> 2, sg = (t & 3) * 32;
        const float sck = scs[k], shk = shs[k];
        float4* hp = (float4*)(ht + k * 128 + sg);
        #pragma unroll
        for (int q = 0; q < 8; q++) {
            float4 v2 = hp[q];
            hp[q] = make_float4(v2.x * sck + shk, v2.y * sck + shk,
                                v2.z * sck + shk, v2.w * sck + shk);
        }
    }
    __syncthreads();

    // ---- M1, M2 (redundant; BN hops are __syncthreads) ----
    mlayer(ht, sp1, sp2, scs, shs, t, Wm1, bm1, gbn1, bbn1);
    mlayer(ht, sp1, sp2, scs, shs, t, Wm2, bm2, gbn2, bbn2);

    // ---- O: 2 graphs per block ----
    if (t < 128) {
        const int gs = t >> 6, o = t & 63;
        const int gg = bid * 2 + gs;
        float a = bo[o];
        #pragma unroll 8
        for (int k = 0; k < 128; k++) a += ht[k * 128 + gg] * Wo[k * 64 + o];
        out[gg * NOUT + o] = a;
    }
}

extern "C" void kernel_launch(void* const* d_in, const int* in_sizes, int n_in,
                              void* d_out, int out_size, void* d_ws, size_t ws_size,
                              hipStream_t stream)
{
    const float* x   = (const float*)d_in[0];
    const float* ew  = (const float*)d_in[2];
    const float* W1  = (const float*)d_in[4];
    const float* b1  = (const float*)d_in[5];
    const float* W2  = (const float*)d_in[6];
    const float* b2  = (const float*)d_in[7];
    const float* Wm0 = (const float*)d_in[8];
    const float* bm0 = (const float*)d_in[9];
    const float* g0  = (const float*)d_in[10];
    const float* be0 = (const float*)d_in[11];
    const float* Wm1 = (const float*)d_in[12];
    const float* bm1 = (const float*)d_in[13];
    const float* g1  = (const float*)d_in[14];
    const float* be1 = (const float*)d_in[15];
    const float* Wm2 = (const float*)d_in[16];
    const float* bm2 = (const float*)d_in[17];
    const float* g2  = (const float*)d_in[18];
    const float* be2 = (const float*)d_in[19];
    const float* Wo  = (const float*)d_in[20];
    const float* bo  = (const float*)d_in[21];

    float* ws    = (float*)d_ws;
    float* part  = ws;                 // 4 * 16384 = 65536 floats (256 KB)
    float* ppart = ws + 65536;         // 16384 floats

    k_front<<<160, 512, 0, stream>>>(x, ew, W1, b1, W2, b2, Wm0, part, ppart);
    k_tail<<<64, 512, 0, stream>>>(part, ppart, bm0,
                                   g0, be0, Wm1, bm1,
                                   g1, be1, Wm2, bm2,
                                   g2, be2, Wo, bo,
                                   (float*)d_out);
}

// Round 10
// 130.590 us; speedup vs baseline: 1.4215x; 1.4215x over previous
//
#include <hip/hip_runtime.h>

#define NG 128      // graphs
#define NPG 64      // nodes per graph
#define IN 16
#define DM 128      // d_model
#define NOUT 64
#define EPG 4096    // edges per graph (64x64)
#define NCH 128     // gemm chunks: 64 k-chunks(80) x 2 f-halves(64)
#define BN_EPS 1e-5f

// ---------------------------------------------------------------------------
// Best-measured configuration (r7: 132.5us). 5 kernels, 4 boundaries.
// Session conclusion: dur = ~82us harness fills + ~21us kernels + ~25us for
// the 4 structural syncs (gemm-reduce + 3 BN-stats hops). In-kernel grid
// barriers == kernel boundaries == ~6us each (r2/r5/r8 A/B); buying syncs
// with redundant compute regresses (r6 +12us, r9 +60us).
// ---------------------------------------------------------------------------

// K_A "front": 256 blocks x 512 threads (8 waves = 2/SIMD latency hiding).
//   blocks 0..127  = conv1 per graph -> pooled -> ppart (Wm0[0:128] product)
//   blocks 128..255 = big-GEMM x/ew chunks (80k x 64f) -> part
__global__ __launch_bounds__(512) void k_front(
    const float* __restrict__ x, const float* __restrict__ ew,
    const float* __restrict__ W1, const float* __restrict__ b1,
    const float* __restrict__ W2, const float* __restrict__ b2,
    const float* __restrict__ Wm0,
    float* __restrict__ part, float* __restrict__ ppart,
    float* __restrict__ stats)
{
    __shared__ __align__(16) float u[16128];   // 63KB union
    const int bid = blockIdx.x, t = threadIdx.x;

    if (bid < 128) {
        // ---------------- conv path (one block per graph) ----------------
        float* ew_s     = u;             // [i][j] 4096 (raw)
        float* x_s      = u + 4096;      // x^T [k][i] 1024
        float* W1_s     = u + 5120;      // [k][f] 2048
        float* P_s      = u + 7168;      // [i][f] 8192 (dinv_i * P)
        float* b1_s     = u + 15360;     // 128
        float* dinv_s   = u + 15488;     // 64
        float* t_s      = u + 15552;     // 64
        float* zp       = u + 4096;      // overlay (x_s/W1_s dead): 16*132
        float* z_full   = u + 15616;     // 128
        float* pooled_s = u + 15744;     // 128
        float* pp4      = u + 4096;      // overlay 2 (zp dead): 512
        const int g = bid;
        if (bid == 0) {
            for (int i = t; i < 768; i += 512) stats[i] = 0.f;
        }
        // stage: ew (vectorized), x transposed (t<256), W1 direct, b1
        {
            const float4* ew4 = (const float4*)(ew + g * EPG);
            float4* ews4 = (float4*)ew_s;
            ews4[t]       = ew4[t];
            ews4[t + 512] = ew4[t + 512];
            if (t < 256) {
                const int xi = t & 63, k4 = (t >> 6) * 4;
                float4 xv = *(const float4*)(x + g * NPG * IN + xi * IN + k4);
                x_s[(k4 + 0) * 64 + xi] = xv.x;
                x_s[(k4 + 1) * 64 + xi] = xv.y;
                x_s[(k4 + 2) * 64 + xi] = xv.z;
                x_s[(k4 + 3) * 64 + xi] = xv.w;
            }
            ((float4*)W1_s)[t] = ((const float4*)W1)[t];   // 512 f4 = 2048
            if (t < 128) b1_s[t] = b1[t];
        }
        __syncthreads();

        // dinv: column sums of raw ew
        if (t < NPG) {
            float s = 0.f;
            #pragma unroll 8
            for (int i = 0; i < NPG; i++) s += ew_s[i * NPG + t];
            dinv_s[t] = (s > 0.f) ? rsqrtf(s) : 0.f;
        }
        __syncthreads();

        // t_s[i] = dinv_i * (sum_j ew[i,j] dinv_j) / 64  (8 waves x 8 rows)
        {
            const int j = t & 63, q = t >> 6;     // q = wave 0..7
            const float dj = dinv_s[j];
            for (int i = q * 8; i < q * 8 + 8; i++) {
                float vv = ew_s[i * NPG + j] * dj;
                #pragma unroll
                for (int off = 32; off > 0; off >>= 1) vv += __shfl_down(vv, off, 64);
                if (j == 0) t_s[i] = dinv_s[i] * vv * (1.f / 64.f);
            }
        }

        // P' = dinv_i * (x @ W1) (64x128x16), 16x32 thread grid, 4x4 acc
        {
            const int it = t & 15, ft = t >> 4;   // ft 0..31
            const int i0 = it * 4, f0 = ft * 4;
            float accp[4][4];
            #pragma unroll
            for (int a = 0; a < 4; a++)
                #pragma unroll
                for (int c = 0; c < 4; c++) accp[a][c] = 0.f;
            #pragma unroll
            for (int k = 0; k < IN; k++) {
                const float4 a4 = *(const float4*)(x_s + k * 64 + i0);
                const float4 b4 = *(const float4*)(W1_s + k * DM + f0);
                const float av[4] = {a4.x, a4.y, a4.z, a4.w};
                const float bv[4] = {b4.x, b4.y, b4.z, b4.w};
                #pragma unroll
                for (int a = 0; a < 4; a++)
                    #pragma unroll
                    for (int c = 0; c < 4; c++) accp[a][c] += av[a] * bv[c];
            }
            #pragma unroll
            for (int a = 0; a < 4; a++) {
                const float di = dinv_s[i0 + a];
                *(float4*)(P_s + (i0 + a) * DM + f0) =
                    make_float4(di * accp[a][0], di * accp[a][1],
                                di * accp[a][2], di * accp[a][3]);
            }
        }
        __syncthreads();

        // aggregation: h[j,f] = relu(dinv_j * sum_k ew[k,j] P'[k,f] + b1[f]);
        // z-partials per thread -> zp. 16x32 grid, 4x4 acc.
        {
            const int jt = t & 15, ft = t >> 4;
            const int j0 = jt * 4, f0 = ft * 4;
            float acc[4][4];
            #pragma unroll
            for (int a = 0; a < 4; a++)
                #pragma unroll
                for (int c = 0; c < 4; c++) acc[a][c] = 0.f;
            #pragma unroll 4
            for (int k = 0; k < 64; k++) {
                const float4 a4 = *(const float4*)(ew_s + k * 64 + j0);
                const float4 b4 = *(const float4*)(P_s + k * DM + f0);
                const float av[4] = {a4.x, a4.y, a4.z, a4.w};
                const float bv[4] = {b4.x, b4.y, b4.z, b4.w};
                #pragma unroll
                for (int a = 0; a < 4; a++)
                    #pragma unroll
                    for (int c = 0; c < 4; c++) acc[a][c] += av[a] * bv[c];
            }
            float zpart[4];
            #pragma unroll
            for (int c = 0; c < 4; c++) zpart[c] = 0.f;
            #pragma unroll
            for (int a = 0; a < 4; a++) {
                const float dj = dinv_s[j0 + a], tj = t_s[j0 + a];
                #pragma unroll
                for (int c = 0; c < 4; c++) {
                    float h = fmaxf(dj * acc[a][c] + b1_s[f0 + c], 0.f);
                    zpart[c] += tj * h;
                }
            }
            *(float4*)(zp + jt * 132 + f0) =
                make_float4(zpart[0], zpart[1], zpart[2], zpart[3]);
        }
        __syncthreads();

        // z (LDS-resident only)
        if (t < 128) {
            float s = 0.f;
            #pragma unroll
            for (int jt = 0; jt < 16; jt++) s += zp[jt * 132 + t];
            z_full[t] = s;
        }
        __syncthreads();

        // pooled = relu(z @ W2 + b2): thread (c = t&127, kh = t>>7 in 0..3)
        {
            const int c = t & 127, kh = t >> 7;
            float acc = 0.f;
            #pragma unroll 8
            for (int k = kh * 32; k < kh * 32 + 32; k++)
                acc += z_full[k] * W2[k * DM + c];
            pp4[kh * 128 + c] = acc;    // overlay: zp dead now
        }
        __syncthreads();
        if (t < 128)
            pooled_s[t] = fmaxf(pp4[t] + pp4[128 + t] + pp4[256 + t] + pp4[384 + t]
                                + b2[t], 0.f);
        __syncthreads();

        // ppart = pooled @ Wm0[0:128,:]
        {
            const int f = t & 127, kh = t >> 7;
            float acc = 0.f;
            #pragma unroll 8
            for (int k = kh * 32; k < kh * 32 + 32; k++)
                acc += pooled_s[k] * Wm0[k * DM + f];
            pp4[kh * 128 + f] = acc;
        }
        __syncthreads();
        if (t < 128)
            ppart[g * DM + t] = pp4[t] + pp4[128 + t] + pp4[256 + t] + pp4[384 + t];
    } else {
        // ---------------- gemm x/ew chunk path (K=80) ----------------
        const int c = bid - 128;
        const int kc = c >> 1, fh = c & 1;
        const int K0 = kc * 80;          // feat col base in x|ew space (0..5120)
        float* a_s = u;                  // [k][g] 80*132 = 10560
        float* b_s = u + 10560;          // [k][fl] 80*64 = 5120

        // reg-batched float4 staging (all loads in flight before LDS writes)
        float4 ra[4], ra2, rb[3];
        #pragma unroll
        for (int it = 0; it < 4; it++) {             // k 0..63: 2048 f4
            int idx = it * 512 + t;
            int gg = idx >> 4, k4 = (idx & 15) << 2;
            int K = K0 + k4;
            const float* src = (K < 1024) ? (x + gg * 1024 + K)
                                          : (ew + gg * 4096 + (K - 1024));
            ra[it] = *(const float4*)src;
        }
        {                                            // k 64..79: 512 f4
            int gg = t >> 2, k4 = 64 + ((t & 3) << 2);
            int K = K0 + k4;
            const float* src = (K < 1024) ? (x + gg * 1024 + K)
                                          : (ew + gg * 4096 + (K - 1024));
            ra2 = *(const float4*)src;
        }
        #pragma unroll
        for (int it = 0; it < 3; it++) {             // Wm0 slice: 1280 f4
            int idx = it * 512 + t;
            if (idx < 1280) {
                int k = idx >> 4, fl4 = (idx & 15) << 2;
                rb[it] = *(const float4*)(Wm0 + (size_t)(128 + K0 + k) * 128
                                          + fh * 64 + fl4);
            }
        }
        #pragma unroll
        for (int it = 0; it < 4; it++) {
            int idx = it * 512 + t;
            int gg = idx >> 4, k4 = (idx & 15) << 2;
            a_s[(k4 + 0) * 132 + gg] = fmaxf(ra[it].x, 0.f);
            a_s[(k4 + 1) * 132 + gg] = fmaxf(ra[it].y, 0.f);
            a_s[(k4 + 2) * 132 + gg] = fmaxf(ra[it].z, 0.f);
            a_s[(k4 + 3) * 132 + gg] = fmaxf(ra[it].w, 0.f);
        }
        {
            int gg = t >> 2, k4 = 64 + ((t & 3) << 2);
            a_s[(k4 + 0) * 132 + gg] = fmaxf(ra2.x, 0.f);
            a_s[(k4 + 1) * 132 + gg] = fmaxf(ra2.y, 0.f);
            a_s[(k4 + 2) * 132 + gg] = fmaxf(ra2.z, 0.f);
            a_s[(k4 + 3) * 132 + gg] = fmaxf(ra2.w, 0.f);
        }
        #pragma unroll
        for (int it = 0; it < 3; it++) {
            int idx = it * 512 + t;
            if (idx < 1280) {
                int k = idx >> 4, fl4 = (idx & 15) << 2;
                *(float4*)(b_s + k * 64 + fl4) = rb[it];
            }
        }
        __syncthreads();

        const int gthr = t & 31, fthr = t >> 5;   // 32 x 16
        const int g0 = gthr * 4, f0 = fthr * 4;
        float acc[4][4];
        #pragma unroll
        for (int i = 0; i < 4; i++)
            #pragma unroll
            for (int jx = 0; jx < 4; jx++) acc[i][jx] = 0.f;

        #pragma unroll 4
        for (int k = 0; k < 80; k++) {
            const float4 a4 = *(const float4*)(a_s + k * 132 + g0);
            const float4 b4 = *(const float4*)(b_s + k * 64 + f0);
            const float av[4] = {a4.x, a4.y, a4.z, a4.w};
            const float bv[4] = {b4.x, b4.y, b4.z, b4.w};
            #pragma unroll
            for (int i = 0; i < 4; i++)
                #pragma unroll
                for (int jx = 0; jx < 4; jx++) acc[i][jx] += av[i] * bv[jx];
        }

        float* pp = part + (size_t)c * 8192;    // [g][fl] 128x64
        #pragma unroll
        for (int i = 0; i < 4; i++)
            *(float4*)(pp + (g0 + i) * 64 + f0) =
                make_float4(acc[i][0], acc[i][1], acc[i][2], acc[i][3]);
    }
}

// ---------------------------------------------------------------------------
// K_B: slim reduce (float4 loads): 128 chunk-partials + ppart + bm0 + relu
// -> v0; BN0 stats atomics. 256 blocks = 32 g-tiles x 8 f-grps.
// ---------------------------------------------------------------------------
__global__ __launch_bounds__(256) void k_reduce_bn0(
    const float* __restrict__ part, const float* __restrict__ ppart,
    const float* __restrict__ bm0, float* __restrict__ v0,
    float* __restrict__ stats0)
{
    __shared__ float r1[1024];    // [ch][gl][16f]
    __shared__ float sv[64], sv2[64];
    const int bx = blockIdx.x, t = threadIdx.x;
    const int fgrp = bx & 7, gt = bx >> 3;
    const int f4 = t & 3, gl = (t >> 2) & 3, ch = t >> 4;
    const int g = gt * 4 + gl;
    const int fbase = fgrp * 16 + f4 * 4;
    const int fh = fbase >> 6, fl = fbase & 63;

    const float4* p = (const float4*)part
                    + ((size_t)(2 * (ch * 4) + fh) * 8192 + g * 64 + fl) / 4;
    float4 v = make_float4(0.f, 0.f, 0.f, 0.f);
    #pragma unroll
    for (int cc = 0; cc < 4; cc++) {
        float4 x4 = p[(size_t)cc * 4096];   // +2*8192 floats per k-chunk
        v.x += x4.x; v.y += x4.y; v.z += x4.z; v.w += x4.w;
    }
    float* r = r1 + ch * 64 + gl * 16 + f4 * 4;
    r[0] = v.x; r[1] = v.y; r[2] = v.z; r[3] = v.w;
    __syncthreads();

    if (t < 64) {
        const int fsub = t & 15, gl2 = t >> 4;
        const int f = fgrp * 16 + fsub, gg = gt * 4 + gl2;
        float s = bm0[f] + ppart[gg * DM + f];
        #pragma unroll
        for (int c2 = 0; c2 < 16; c2++) s += r1[c2 * 64 + gl2 * 16 + fsub];
        s = fmaxf(s, 0.f);
        v0[gg * DM + f] = s;
        sv[t] = s; sv2[t] = s * s;
    }
    __syncthreads();
    if (t < 16) {
        float s1 = sv[t] + sv[t + 16] + sv[t + 32] + sv[t + 48];
        float s2 = sv2[t] + sv2[t + 16] + sv2[t + 32] + sv2[t + 48];
        atomicAdd(&stats0[(fgrp * 16 + t) * 2], s1);
        atomicAdd(&stats0[(fgrp * 16 + t) * 2 + 1], s2);
    }
}

// ---------------------------------------------------------------------------
// K5/K6: one MLP layer. 256 blocks = 128 f-cols x 2 graph-halves.
// ---------------------------------------------------------------------------
__global__ __launch_bounds__(256) void k_mlp(
    const float* __restrict__ vin, const float* __restrict__ statsin,
    const float* __restrict__ gbn, const float* __restrict__ bbn,
    const float* __restrict__ W, const float* __restrict__ bias,
    float* __restrict__ vout, float* __restrict__ statsout)
{
    __shared__ float scale_s[128], shift_s[128];
    __shared__ float wcol[128];
    __shared__ float pc[256];
    __shared__ float h_s[64 * 129];
    const int b = blockIdx.x, t = threadIdx.x;
    const int f = b & 127, gh = b >> 7;
    if (t < 128) {
        float s1 = statsin[t * 2], s2 = statsin[t * 2 + 1];
        float m = s1 * (1.f / 128.f);
        float var = s2 * (1.f / 128.f) - m * m;
        float sc = gbn[t] * rsqrtf(var + BN_EPS);
        scale_s[t] = sc;
        shift_s[t] = bbn[t] - m * sc;
        wcol[t] = W[t * 128 + f];
    }
    __syncthreads();
    const int g0r = gh * 64;
    const float4* vin4 = (const float4*)(vin + g0r * 128);
    #pragma unroll
    for (int it = 0; it < 8; ++it) {
        int idx = it * 256 + t;            // 2048 float4 = 64 rows x 128
        int gl = idx >> 5, k4 = (idx & 31) * 4;
        float4 vv = vin4[idx];
        float* hp = h_s + gl * 129 + k4;
        hp[0] = vv.x * scale_s[k4 + 0] + shift_s[k4 + 0];
        hp[1] = vv.y * scale_s[k4 + 1] + shift_s[k4 + 1];
        hp[2] = vv.z * scale_s[k4 + 2] + shift_s[k4 + 2];
        hp[3] = vv.w * scale_s[k4 + 3] + shift_s[k4 + 3];
    }
    __syncthreads();
    {
        const int gl = t & 63, kh = t >> 6;
        float acc = 0.f;
        #pragma unroll 8
        for (int k = kh * 32; k < kh * 32 + 32; ++k) acc += h_s[gl * 129 + k] * wcol[k];
        pc[gl * 4 + kh] = acc;
    }
    __syncthreads();
    if (t < 64) {   // wave 0
        float v = fmaxf(pc[t * 4] + pc[t * 4 + 1] + pc[t * 4 + 2] + pc[t * 4 + 3]
                        + bias[f], 0.f);
        vout[(size_t)(g0r + t) * 128 + f] = v;
        float s1 = v, s2 = v * v;
        #pragma unroll
        for (int off = 32; off > 0; off >>= 1) {
            s1 += __shfl_down(s1, off, 64);
            s2 += __shfl_down(s2, off, 64);
        }
        if (t == 0) {
            atomicAdd(&statsout[f * 2], s1);
            atomicAdd(&statsout[f * 2 + 1], s2);
        }
    }
}

// ---------------------------------------------------------------------------
// K7: output layer (BN2 folded at load). Block = 2 graph rows.
// ---------------------------------------------------------------------------
__global__ __launch_bounds__(128) void k_out(
    const float* __restrict__ vin, const float* __restrict__ statsin,
    const float* __restrict__ gbn, const float* __restrict__ bbn,
    const float* __restrict__ Wo, const float* __restrict__ bo,
    float* __restrict__ out)
{
    __shared__ __align__(16) float Wo_s[128 * 64];   // 32KB
    __shared__ float vrow[2][128];
    __shared__ float scale_s[128], shift_s[128];
    const int b = blockIdx.x, t = threadIdx.x, g0 = b * 2;
    {
        float s1 = statsin[t * 2], s2 = statsin[t * 2 + 1];
        float m = s1 * (1.f / 128.f);
        float var = s2 * (1.f / 128.f) - m * m;
        float sc = gbn[t] * rsqrtf(var + BN_EPS);
        scale_s[t] = sc;
        shift_s[t] = bbn[t] - m * sc;
    }
    __syncthreads();
    {
        const float4* wo4 = (const float4*)Wo;
        float4* wos4 = (float4*)Wo_s;
        #pragma unroll
        for (int it = 0; it < 16; it++) wos4[it * 128 + t] = wo4[it * 128 + t];
    }
    if (t < 64) {
        int g2 = t >> 5, k4 = (t & 31) * 4;
        float4 vv = ((const float4*)(vin + g0 * 128))[t];
        vrow[g2][k4 + 0] = vv.x * scale_s[k4 + 0] + shift_s[k4 + 0];
        vrow[g2][k4 + 1] = vv.y * scale_s[k4 + 1] + shift_s[k4 + 1];
        vrow[g2][k4 + 2] = vv.z * scale_s[k4 + 2] + shift_s[k4 + 2];
        vrow[g2][k4 + 3] = vv.w * scale_s[k4 + 3] + shift_s[k4 + 3];
    }
    __syncthreads();
    const int g2 = t >> 6, o = t & 63;
    float acc = bo[o];
    #pragma unroll 8
    for (int k = 0; k < 128; k++) acc += vrow[g2][k] * Wo_s[k * 64 + o];
    out[(g0 + g2) * NOUT + o] = acc;
}

extern "C" void kernel_launch(void* const* d_in, const int* in_sizes, int n_in,
                              void* d_out, int out_size, void* d_ws, size_t ws_size,
                              hipStream_t stream)
{
    const float* x   = (const float*)d_in[0];
    const float* ew  = (const float*)d_in[2];
    const float* W1  = (const float*)d_in[4];
    const float* b1  = (const float*)d_in[5];
    const float* W2  = (const float*)d_in[6];
    const float* b2  = (const float*)d_in[7];
    const float* Wm0 = (const float*)d_in[8];
    const float* bm0 = (const float*)d_in[9];
    const float* g0  = (const float*)d_in[10];
    const float* be0 = (const float*)d_in[11];
    const float* Wm1 = (const float*)d_in[12];
    const float* bm1 = (const float*)d_in[13];
    const float* g1  = (const float*)d_in[14];
    const float* be1 = (const float*)d_in[15];
    const float* Wm2 = (const float*)d_in[16];
    const float* bm2 = (const float*)d_in[17];
    const float* g2  = (const float*)d_in[18];
    const float* be2 = (const float*)d_in[19];
    const float* Wo  = (const float*)d_in[20];
    const float* bo  = (const float*)d_in[21];

    float* ws     = (float*)d_ws;
    float* part   = ws;                       // 128*8192 = 1048576
    float* ppartb = part + NCH * 8192;        // 16384
    float* v0     = ppartb + 16384;           // 16384
    float* v1     = v0 + 16384;               // 16384
    float* v2     = v1 + 16384;               // 16384
    float* stats  = v2 + 16384;               // 768 (stats0|stats1|stats2)

    k_front<<<256, 512, 0, stream>>>(x, ew, W1, b1, W2, b2, Wm0, part, ppartb, stats);
    k_reduce_bn0<<<256, 256, 0, stream>>>(part, ppartb, bm0, v0, stats);
    k_mlp<<<256, 256, 0, stream>>>(v0, stats,       g0, be0, Wm1, bm1, v1, stats + 256);
    k_mlp<<<256, 256, 0, stream>>>(v1, stats + 256, g1, be1, Wm2, bm2, v2, stats + 512);
    k_out<<<NOUT, 128, 0, stream>>>(v2, stats + 512, g2, be2, Wo, bo, (float*)d_out);
}